// Round 5
// baseline (321.706 us; speedup 1.0000x reference)
//
#include <hip/hip_runtime.h>
#include <hip/hip_cooperative_groups.h>

namespace cg = cooperative_groups;

#define NN 1024
#define FF 64
#define CC 4
#define EE 32768
#define HH 256

// ---- workspace layout (units of 4-byte words) ----
#define OFF_CNT   0u        // 4096 i
#define OFF_OFFS  4096u     // 4097 i
#define OFF_CUR   8200u     // 4096 i
#define OFF_SRT   12304u    // 262144 (int2 per edge, sorted by (c,dst))
#define OFF_P     274448u   // 262144 f
#define OFF_Q     536592u   // 262144 f
// end 798736 words = 3.2 MB

// ---------------------------------------------------------------------------
// Cooperative preprocessing: zero-cnt -> count -> scan -> bucket -> node MLP.
// 256 blocks x 1024 threads, co-resident (1 block/CU), grid.sync between
// phases. Produces srt (sorted edges), offs (bucket ranges), P, Q.
__global__ __launch_bounds__(1024)
void k_pre(const float* __restrict__ x, const int* __restrict__ ei,
           const float* __restrict__ ew,
           const float* __restrict__ Wn1, const float* __restrict__ bn1,
           const float* __restrict__ Wn2, const float* __restrict__ bn2,
           const float* __restrict__ We1, const float* __restrict__ be1,
           const float* __restrict__ epsp,
           int* __restrict__ cnt, int* __restrict__ offs, int* __restrict__ cur,
           int2* __restrict__ srt, float* __restrict__ P, float* __restrict__ Q)
{
    cg::grid_group grid = cg::this_grid();
    const int tid = threadIdx.x;
    const int b = blockIdx.x;
    const unsigned g = b * 1024u + tid;

    __shared__ float hval[4][256];
    __shared__ float hidl[4][256];
    __shared__ float part[4][4][64];
    __shared__ float xnl[4][64];
    __shared__ int wsum[16];

    // ---- phase 0: zero bucket counters
    if (g < 4096) cnt[g] = 0;
    grid.sync();

    // ---- phase 1: count (c,dst) buckets
    if (g < CC * EE) {
        unsigned e = g & (EE - 1u), c = g >> 15;
        int dst = ei[c * 2 * EE + EE + e];
        atomicAdd(&cnt[c * NN + dst], 1);
    }
    grid.sync();

    // ---- phase 2: exclusive scan over 4096 counts (block 0 only)
    if (b == 0) {
        int4 v = ((const int4*)cnt)[tid];
        int s = v.x + v.y + v.z + v.w;
        int incl = s;
#pragma unroll
        for (int d = 1; d < 64; d <<= 1) {
            int t2 = __shfl_up(incl, d, 64);
            if ((tid & 63) >= d) incl += t2;
        }
        const int w = tid >> 6;
        if ((tid & 63) == 63) wsum[w] = incl;
        __syncthreads();
        int base = incl - s;
        for (int ww = 0; ww < w; ++ww) base += wsum[ww];
        offs[tid * 4]     = base;             cur[tid * 4]     = base;
        offs[tid * 4 + 1] = base + v.x;       cur[tid * 4 + 1] = base + v.x;
        offs[tid * 4 + 2] = base + v.x + v.y; cur[tid * 4 + 2] = base + v.x + v.y;
        offs[tid * 4 + 3] = base + v.x + v.y + v.z;
        cur[tid * 4 + 3]  = base + v.x + v.y + v.z;
        if (tid == 1023) offs[4096] = base + s;
    }
    grid.sync();

    // ---- phase 3: bucket-scatter edges (one int2 store per edge)
    if (g < CC * EE) {
        unsigned e = g & (EE - 1u), c = g >> 15;
        int src = ei[c * 2 * EE + e];
        int dst = ei[c * 2 * EE + EE + e];
        float w = ew[c * EE + e];
        int pos = atomicAdd(&cur[c * NN + dst], 1);
        srt[pos] = make_int2(src, __float_as_int(w));
    }
    grid.sync();

    // ---- phase 4: fused node pipeline, 4 nodes per block
    const int n0 = b * 4;
    {
        // gather: wave w -> (c = w&3, node = n0 + (w>>2)), lane = f
        const int w = tid >> 6, lane = tid & 63;
        const int c = w & 3, nn = w >> 2;
        const int bg = c * NN + (n0 + nn);
        const int beg = offs[bg], end = offs[bg + 1];
        float acc = 0.f;
        for (int k = beg; k < end; ++k) {
            int2 e2 = srt[k];
            acc += x[e2.x * FF + lane] * __int_as_float(e2.y);
        }
        const float ope = 1.0f + epsp[0];
        hval[nn][c * 64 + lane] = acc + ope * x[(n0 + nn) * FF + lane];
    }
    __syncthreads();

    // mlp1: hid = relu(bn1 + hval @ Wn1)
    {
        const int nn = tid >> 8, h = tid & 255;
        float acc = bn1[h];
#pragma unroll 8
        for (int k = 0; k < 256; ++k)
            acc += hval[nn][k] * Wn1[k * 256 + h];
        hidl[nn][h] = fmaxf(acc, 0.f);
    }
    __syncthreads();

    // mlp2 partials over 4 k-quarters
    {
        const int kq = tid >> 8, nn = (tid >> 6) & 3, f = tid & 63;
        float p = 0.f;
#pragma unroll 8
        for (int k = kq * 64; k < kq * 64 + 64; ++k)
            p += hidl[nn][k] * Wn2[k * 64 + f];
        part[kq][nn][f] = p;
    }
    __syncthreads();
    if (tid < 256) {
        const int nn = tid >> 6, f = tid & 63;
        xnl[nn][f] = bn2[f] + part[0][nn][f] + part[1][nn][f]
                             + part[2][nn][f] + part[3][nn][f];
    }
    __syncthreads();

    // P/Q projection
    {
        const int r = tid >> 8, h = tid & 255;
        float p = be1[h], q = 0.f;
#pragma unroll 8
        for (int f = 0; f < 64; ++f) {
            float xv = xnl[r][f];
            p += xv * We1[(4 + f) * 256 + h];
            q += xv * We1[(68 + f) * 256 + h];
        }
        P[(n0 + r) * 256 + h] = p;
        Q[(n0 + r) * 256 + h] = q;
    }
}

// ---------------------------------------------------------------------------
// Edge MLP: uniform pass relu(P+Q)@We2 + compacted sparse fixup.
// a-tile built by scanning the (c,dst)-sorted list for dst in the j-tile,
// filtering src in the i-tile. Fixup corrections carried in registers;
// correction exchange overlays the dead Pl/Ql buffer. LDS 34.3 KB ->
// 4 blocks/CU.
__global__ __launch_bounds__(256, 4)
void k_edge_mlp(const float* __restrict__ P, const float* __restrict__ Q,
                const int* __restrict__ offs, const int2* __restrict__ srt,
                const float* __restrict__ We1, const float* __restrict__ We2,
                const float* __restrict__ be2, float* __restrict__ out)
{
    __shared__ float4 aT[32 * 32];      // 16 KB dense a-tile [li*32+lj]
    __shared__ float4 PQbuf[1024];      // 16 KB: Pl = [0,512), Ql = [512,1024); corr overlay at end
    __shared__ unsigned short list[1024];
    __shared__ int nList;

    const int tid = threadIdx.x;
    const int bi = blockIdx.y, bj = blockIdx.x;
    const int iBase = bi * 32, jBase = bj * 32;

    // phase 0: zero aT, nList
#pragma unroll
    for (int u = 0; u < 4; ++u)
        aT[tid + u * 256] = make_float4(0.f, 0.f, 0.f, 0.f);
    if (tid == 0) nList = 0;
    __syncthreads();

    // phase 1: build a-tile from the (c,dst)-sorted edge list
    {
        float* aTf = (float*)aT;
        const int wv = tid >> 6, lane = tid & 63;
        for (int bkt = wv; bkt < 128; bkt += 4) {
            const int c = bkt >> 5, dl = bkt & 31;
            const int bg = c * NN + (jBase + dl);
            const int beg = offs[bg], end = offs[bg + 1];
            for (int k = beg + lane; k < end; k += 64) {
                int2 e2 = srt[k];
                if ((e2.x >> 5) == bi) {
                    int li = e2.x & 31;
                    atomicAdd(&aTf[(li * 32 + dl) * 4 + c], __int_as_float(e2.y));
                }
            }
        }
    }
    __syncthreads();

    // phase 2: compact nonzero pairs
#pragma unroll
    for (int u = 0; u < 4; ++u) {
        int p = tid * 4 + u;
        float4 a4 = aT[p];
        if (a4.x != 0.f || a4.y != 0.f || a4.z != 0.f || a4.w != 0.f) {
            int idx = atomicAdd(&nList, 1);
            list[idx] = (unsigned short)p;
        }
    }
    __syncthreads();
    const int nL = nList;

    // claim fixup entries into registers (statically-indexed slots)
    int myp[4];
    float4 mya[4], mycc[4];
#pragma unroll
    for (int k = 0; k < 4; ++k) {
        int en = tid + k * 256;
        if (en < nL) { myp[k] = list[en]; mya[k] = aT[myp[k]]; }
        else         { myp[k] = -1; mya[k] = make_float4(0.f, 0.f, 0.f, 0.f); }
        mycc[k] = make_float4(0.f, 0.f, 0.f, 0.f);
    }

    const int tx = tid & 15, ty = tid >> 4;
    const int psw = ty & 7, qsw = tx & 7;

    float4 acc[2][2];
#pragma unroll
    for (int ii = 0; ii < 2; ++ii)
#pragma unroll
        for (int jj = 0; jj < 2; ++jj)
            acc[ii][jj] = make_float4(0.f, 0.f, 0.f, 0.f);

    for (int hc = 0; hc < 4; ++hc) {
        // stage P/Q chunk (loop-end barrier protects previous readers)
#pragma unroll
        for (int u = 0; u < 2; ++u) {
            int idx = tid + u * 256;
            int row = idx >> 4, q = idx & 15;
            int ph = q ^ ((row >> 1) & 7);
            PQbuf[row * 16 + ph]       = *(const float4*)(P + (iBase + row) * 256 + hc * 64 + q * 4);
            PQbuf[512 + row * 16 + ph] = *(const float4*)(Q + (jBase + row) * 256 + hc * 64 + q * 4);
        }
        __syncthreads();

        // uniform pass: relu(P+Q) @ We2, no a-term
#pragma unroll 4
        for (int q = 0; q < 16; ++q) {
            float4 w2[4];
#pragma unroll
            for (int k = 0; k < 4; ++k)
                w2[k] = *(const float4*)(We2 + (hc * 64 + q * 4 + k) * 4);
            float4 p[2], qv[2];
#pragma unroll
            for (int r = 0; r < 2; ++r) p[r]  = PQbuf[(ty * 2 + r) * 16 + (q ^ psw)];
#pragma unroll
            for (int r = 0; r < 2; ++r) qv[r] = PQbuf[512 + (tx * 2 + r) * 16 + (q ^ qsw)];
#pragma unroll
            for (int ii = 0; ii < 2; ++ii) {
#pragma unroll
                for (int jj = 0; jj < 2; ++jj) {
                    float v0 = fmaxf(p[ii].x + qv[jj].x, 0.f);
                    float v1 = fmaxf(p[ii].y + qv[jj].y, 0.f);
                    float v2 = fmaxf(p[ii].z + qv[jj].z, 0.f);
                    float v3 = fmaxf(p[ii].w + qv[jj].w, 0.f);
                    acc[ii][jj].x += v0 * w2[0].x + v1 * w2[1].x + v2 * w2[2].x + v3 * w2[3].x;
                    acc[ii][jj].y += v0 * w2[0].y + v1 * w2[1].y + v2 * w2[2].y + v3 * w2[3].y;
                    acc[ii][jj].z += v0 * w2[0].z + v1 * w2[1].z + v2 * w2[2].z + v3 * w2[3].z;
                    acc[ii][jj].w += v0 * w2[0].w + v1 * w2[1].w + v2 * w2[2].w + v3 * w2[3].w;
                }
            }
        }

        // sparse fixup: register-resident per-entry corrections
#pragma unroll
        for (int k = 0; k < 4; ++k) {
            if (myp[k] < 0) continue;
            const int li = myp[k] >> 5, lj = myp[k] & 31;
            const int ps2 = (li >> 1) & 7, qs2 = (lj >> 1) & 7;
            const float4 a4 = mya[k];
            float4 cc = mycc[k];
#pragma unroll 4
            for (int q = 0; q < 16; ++q) {
                float4 w1[4], w2[4];
#pragma unroll
                for (int c = 0; c < 4; ++c)
                    w1[c] = *(const float4*)(We1 + c * 256 + hc * 64 + q * 4);
#pragma unroll
                for (int kk = 0; kk < 4; ++kk)
                    w2[kk] = *(const float4*)(We2 + (hc * 64 + q * 4 + kk) * 4);
                float4 pv = PQbuf[li * 16 + (q ^ ps2)];
                float4 qv = PQbuf[512 + lj * 16 + (q ^ qs2)];
                float s0 = a4.x * w1[0].x + a4.y * w1[1].x + a4.z * w1[2].x + a4.w * w1[3].x;
                float s1 = a4.x * w1[0].y + a4.y * w1[1].y + a4.z * w1[2].y + a4.w * w1[3].y;
                float s2 = a4.x * w1[0].z + a4.y * w1[1].z + a4.z * w1[2].z + a4.w * w1[3].z;
                float s3 = a4.x * w1[0].w + a4.y * w1[1].w + a4.z * w1[2].w + a4.w * w1[3].w;
                float b0 = pv.x + qv.x, b1 = pv.y + qv.y, b2_ = pv.z + qv.z, b3 = pv.w + qv.w;
                float d0 = fmaxf(b0 + s0, 0.f) - fmaxf(b0, 0.f);
                float d1 = fmaxf(b1 + s1, 0.f) - fmaxf(b1, 0.f);
                float d2 = fmaxf(b2_ + s2, 0.f) - fmaxf(b2_, 0.f);
                float d3 = fmaxf(b3 + s3, 0.f) - fmaxf(b3, 0.f);
                cc.x += d0 * w2[0].x + d1 * w2[1].x + d2 * w2[2].x + d3 * w2[3].x;
                cc.y += d0 * w2[0].y + d1 * w2[1].y + d2 * w2[2].y + d3 * w2[3].y;
                cc.z += d0 * w2[0].z + d1 * w2[1].z + d2 * w2[2].z + d3 * w2[3].z;
                cc.w += d0 * w2[0].w + d1 * w2[1].w + d2 * w2[2].w + d3 * w2[3].w;
            }
            mycc[k] = cc;
        }
        __syncthreads();
    }

    // correction exchange: overlay corr onto the dead PQbuf
    float4* corr = PQbuf;
#pragma unroll
    for (int u = 0; u < 4; ++u)
        corr[tid + u * 256] = make_float4(0.f, 0.f, 0.f, 0.f);
    __syncthreads();
#pragma unroll
    for (int k = 0; k < 4; ++k)
        if (myp[k] >= 0) corr[myp[k]] = mycc[k];   // single writer per pair
    __syncthreads();

    const float4 b2 = *(const float4*)be2;
#pragma unroll
    for (int ii = 0; ii < 2; ++ii)
#pragma unroll
        for (int jj = 0; jj < 2; ++jj) {
            int p = (ty * 2 + ii) * 32 + (tx * 2 + jj);
            float4 cr = corr[p];
            float4 o = acc[ii][jj];
            o.x += b2.x + cr.x; o.y += b2.y + cr.y;
            o.z += b2.z + cr.z; o.w += b2.w + cr.w;
            *(float4*)(out + ((size_t)(iBase + ty * 2 + ii) * NN + (jBase + tx * 2 + jj)) * 4) = o;
        }
}

// ---------------------------------------------------------------------------
extern "C" void kernel_launch(void* const* d_in, const int* in_sizes, int n_in,
                              void* d_out, int out_size, void* d_ws, size_t ws_size,
                              hipStream_t stream)
{
    (void)in_sizes; (void)n_in; (void)out_size; (void)ws_size;
    const float* x   = (const float*)d_in[0];
    const int*   ei  = (const int*)d_in[1];
    const float* ew  = (const float*)d_in[2];
    const float* Wn1 = (const float*)d_in[3];
    const float* bn1 = (const float*)d_in[4];
    const float* Wn2 = (const float*)d_in[5];
    const float* bn2 = (const float*)d_in[6];
    const float* We1 = (const float*)d_in[7];
    const float* be1 = (const float*)d_in[8];
    const float* We2 = (const float*)d_in[9];
    const float* be2 = (const float*)d_in[10];
    const float* eps = (const float*)d_in[11];
    float* out = (float*)d_out;

    float* ws = (float*)d_ws;
    int*  cnt  = (int*)(ws + OFF_CNT);
    int*  offs = (int*)(ws + OFF_OFFS);
    int*  cur  = (int*)(ws + OFF_CUR);
    int2* srt  = (int2*)(ws + OFF_SRT);
    float* Pb  = ws + OFF_P;
    float* Qb  = ws + OFF_Q;

    void* ka[] = {
        (void*)&x, (void*)&ei, (void*)&ew,
        (void*)&Wn1, (void*)&bn1, (void*)&Wn2, (void*)&bn2,
        (void*)&We1, (void*)&be1, (void*)&eps,
        (void*)&cnt, (void*)&offs, (void*)&cur, (void*)&srt,
        (void*)&Pb, (void*)&Qb
    };
    hipLaunchCooperativeKernel((void*)k_pre, dim3(256), dim3(1024), ka, 0, stream);

    dim3 g(NN / 32, NN / 32);
    k_edge_mlp<<<g, 256, 0, stream>>>(Pb, Qb, offs, srt, We1, We2, be2, out);
}

// Round 6
// 250.440 us; speedup vs baseline: 1.2846x; 1.2846x over previous
//
#include <hip/hip_runtime.h>

#define NN 1024
#define FF 64
#define CC 4
#define EE 32768
#define HH 256

// ---- workspace layout (units of 4-byte words) ----
#define OFF_PART  0u        // 64*1024 i  per-block histogram partials -> block bases
#define OFF_OFFS  65536u    // 1025 i     tile bucket starts
#define OFF_SRT   66564u    // 131072 int2 tile-sorted edges (meta, w)
#define OFF_P     328708u   // 262144 f
#define OFF_Q     590852u   // 262144 f
// end 852996 words = 3.4 MB

// ---------------------------------------------------------------------------
// Sort pass 1: per-block LDS histogram over 1024 (itile,jtile) buckets.
// 64 blocks x 1024 threads, 2048 edges/block. No contended global atomics.
__global__ __launch_bounds__(1024)
void k_hist(const int* __restrict__ ei, int* __restrict__ partial)
{
    __shared__ int h[1024];
    const int tid = threadIdx.x, blk = blockIdx.x;
    h[tid] = 0;
    __syncthreads();
#pragma unroll
    for (int u = 0; u < 2; ++u) {
        int t = blk * 2048 + u * 1024 + tid;
        int e = t & (EE - 1), c = t >> 15;
        int src = ei[c * 2 * EE + e];
        int dst = ei[c * 2 * EE + EE + e];
        atomicAdd(&h[(src >> 5) * 32 + (dst >> 5)], 1);
    }
    __syncthreads();
    partial[blk * 1024 + tid] = h[tid];
}

// Sort pass 2: turn partials into per-block bases + bucket offsets. 1 block.
__global__ __launch_bounds__(1024)
void k_offsets(int* __restrict__ partial, int* __restrict__ offs)
{
    __shared__ int wsum[16];
    const int b = threadIdx.x;
    int run = 0;
    for (int blk = 0; blk < 64; ++blk) {
        int v = partial[blk * 1024 + b];
        partial[blk * 1024 + b] = run;   // within-bucket prefix over blocks
        run += v;
    }
    int incl = run;
#pragma unroll
    for (int d = 1; d < 64; d <<= 1) {
        int v = __shfl_up(incl, d, 64);
        if ((b & 63) >= d) incl += v;
    }
    const int w = b >> 6;
    if ((b & 63) == 63) wsum[w] = incl;
    __syncthreads();
    int base = incl - run;
    for (int ww = 0; ww < w; ++ww) base += wsum[ww];
    offs[b] = base;
    if (b == 1023) offs[1024] = base + run;
    for (int blk = 0; blk < 64; ++blk) partial[blk * 1024 + b] += base;
}

// Sort pass 3: scatter with LDS local ranks (same edge partition as k_hist).
__global__ __launch_bounds__(1024)
void k_scatter(const int* __restrict__ ei, const float* __restrict__ ew,
               const int* __restrict__ partial, int2* __restrict__ srt)
{
    __shared__ int cnt[1024];
    const int tid = threadIdx.x, blk = blockIdx.x;
    cnt[tid] = 0;
    __syncthreads();
#pragma unroll
    for (int u = 0; u < 2; ++u) {
        int t = blk * 2048 + u * 1024 + tid;
        int e = t & (EE - 1), c = t >> 15;
        int src = ei[c * 2 * EE + e];
        int dst = ei[c * 2 * EE + EE + e];
        float w = ew[c * EE + e];
        int bkt = (src >> 5) * 32 + (dst >> 5);
        int r = atomicAdd(&cnt[bkt], 1);
        srt[partial[blk * 1024 + bkt] + r] =
            make_int2(((src & 31) << 7) | ((dst & 31) << 2) | c, __float_as_int(w));
    }
}

// ---------------------------------------------------------------------------
// Node pipeline, sort-free: scan-filter gather -> mlp1 -> mlp2 -> P/Q.
// 256 blocks x 1024 threads (4 nodes/block). Scans all edge dsts (L2), compacts
// ~512 matches to LDS, accumulates agg via LDS atomics. No dependencies.
__global__ __launch_bounds__(1024)
void k_node(const float* __restrict__ x, const int* __restrict__ ei,
            const float* __restrict__ ew,
            const float* __restrict__ Wn1, const float* __restrict__ bn1,
            const float* __restrict__ Wn2, const float* __restrict__ bn2,
            const float* __restrict__ We1, const float* __restrict__ be1,
            const float* __restrict__ epsp,
            float* __restrict__ P, float* __restrict__ Q)
{
    __shared__ float hval[4][256];    // doubles as agg accumulator
    __shared__ float hidl[4][256];
    __shared__ float part[4][4][64];
    __shared__ float xnl[4][64];
    __shared__ int2 list[1024];
    __shared__ int nM;
    const int tid = threadIdx.x;
    const int n0 = blockIdx.x * 4;

    ((float*)hval)[tid] = 0.f;
    if (tid == 0) nM = 0;
    __syncthreads();

    // stage 1: scan all edges' dst, compact matches (dst in [n0, n0+4))
    for (int u = 0; u < 32; ++u) {
        int t4 = u * 4096 + tid * 4;
        int e = t4 & (EE - 1), c = t4 >> 15;
        int4 d4 = *(const int4*)(ei + c * 2 * EE + EE + e);
        unsigned m0 = (unsigned)(d4.x - n0), m1 = (unsigned)(d4.y - n0);
        unsigned m2 = (unsigned)(d4.z - n0), m3 = (unsigned)(d4.w - n0);
        if ((m0 < 4u) | (m1 < 4u) | (m2 < 4u) | (m3 < 4u)) {
            unsigned mm[4] = {m0, m1, m2, m3};
#pragma unroll
            for (int k = 0; k < 4; ++k) {
                if (mm[k] < 4u) {
                    int src = ei[c * 2 * EE + e + k];
                    float w = ew[c * EE + e + k];
                    int idx = atomicAdd(&nM, 1);
                    list[idx] = make_int2((mm[k] << 12) | (c << 10) | src, __float_as_int(w));
                }
            }
        }
    }
    __syncthreads();

    // stage 2: wave-distributed accumulation, lane = f
    {
        const int wv = tid >> 6, lane = tid & 63;
        const int n = nM;
        for (int idx = wv; idx < n; idx += 16) {
            int2 e2 = list[idx];
            int nn = (e2.x >> 12) & 3, c = (e2.x >> 10) & 3, src = e2.x & 1023;
            atomicAdd(&hval[nn][c * 64 + lane],
                      __int_as_float(e2.y) * x[src * FF + lane]);
        }
    }
    __syncthreads();

    // stage 3: add self term
    {
        const float ope = 1.0f + epsp[0];
        const int nn = tid >> 8;
        ((float*)hval)[tid] += ope * x[(n0 + nn) * FF + (tid & 63)];
    }
    __syncthreads();

    // mlp1: hid = relu(bn1 + hval @ Wn1)
    {
        const int nn = tid >> 8, h = tid & 255;
        float acc = bn1[h];
#pragma unroll 8
        for (int k = 0; k < 256; ++k)
            acc += hval[nn][k] * Wn1[k * 256 + h];
        hidl[nn][h] = fmaxf(acc, 0.f);
    }
    __syncthreads();

    // mlp2 partials over 4 k-quarters
    {
        const int kq = tid >> 8, nn = (tid >> 6) & 3, f = tid & 63;
        float p = 0.f;
#pragma unroll 8
        for (int k = kq * 64; k < kq * 64 + 64; ++k)
            p += hidl[nn][k] * Wn2[k * 64 + f];
        part[kq][nn][f] = p;
    }
    __syncthreads();
    if (tid < 256) {
        const int nn = tid >> 6, f = tid & 63;
        xnl[nn][f] = bn2[f] + part[0][nn][f] + part[1][nn][f]
                             + part[2][nn][f] + part[3][nn][f];
    }
    __syncthreads();

    // P/Q projection
    {
        const int r = tid >> 8, h = tid & 255;
        float p = be1[h], q = 0.f;
#pragma unroll 8
        for (int f = 0; f < 64; ++f) {
            float xv = xnl[r][f];
            p += xv * We1[(4 + f) * 256 + h];
            q += xv * We1[(68 + f) * 256 + h];
        }
        P[(n0 + r) * 256 + h] = p;
        Q[(n0 + r) * 256 + h] = q;
    }
}

// ---------------------------------------------------------------------------
// Edge MLP: uniform pass relu(P+Q)@We2 + compacted sparse fixup from the
// exact per-tile edge bucket. Fixup corrections in registers; LDS 34.3 KB.
__global__ __launch_bounds__(256, 4)
void k_edge_mlp(const float* __restrict__ P, const float* __restrict__ Q,
                const int* __restrict__ toffs, const int2* __restrict__ srt,
                const float* __restrict__ We1, const float* __restrict__ We2,
                const float* __restrict__ be2, float* __restrict__ out)
{
    __shared__ float4 aT[32 * 32];      // 16 KB dense a-tile [li*32+lj]
    __shared__ float4 PQbuf[1024];      // 16 KB: Pl [0,512), Ql [512,1024); corr overlay later
    __shared__ unsigned short list[1024];
    __shared__ int nList;

    const int tid = threadIdx.x;
    const int bi = blockIdx.y, bj = blockIdx.x;
    const int iBase = bi * 32, jBase = bj * 32;

#pragma unroll
    for (int u = 0; u < 4; ++u)
        aT[tid + u * 256] = make_float4(0.f, 0.f, 0.f, 0.f);
    if (tid == 0) nList = 0;
    __syncthreads();

    // phase 1: build a-tile from this tile's exact bucket
    {
        const int tile = bi * 32 + bj;
        const int beg = toffs[tile], end = toffs[tile + 1];
        float* aTf = (float*)aT;
        for (int k = beg + tid; k < end; k += 256) {
            int2 e2 = srt[k];
            int li = (e2.x >> 7) & 31, lj = (e2.x >> 2) & 31, c = e2.x & 3;
            atomicAdd(&aTf[(li * 32 + lj) * 4 + c], __int_as_float(e2.y));
        }
    }
    __syncthreads();

    // phase 2: compact nonzero pairs
#pragma unroll
    for (int u = 0; u < 4; ++u) {
        int p = tid * 4 + u;
        float4 a4 = aT[p];
        if (a4.x != 0.f || a4.y != 0.f || a4.z != 0.f || a4.w != 0.f) {
            int idx = atomicAdd(&nList, 1);
            list[idx] = (unsigned short)p;
        }
    }
    __syncthreads();
    const int nL = nList;

    // claim fixup entries into registers
    int myp[4];
    float4 mya[4], mycc[4];
#pragma unroll
    for (int k = 0; k < 4; ++k) {
        int en = tid + k * 256;
        if (en < nL) { myp[k] = list[en]; mya[k] = aT[myp[k]]; }
        else         { myp[k] = -1; mya[k] = make_float4(0.f, 0.f, 0.f, 0.f); }
        mycc[k] = make_float4(0.f, 0.f, 0.f, 0.f);
    }

    const int tx = tid & 15, ty = tid >> 4;
    const int psw = ty & 7, qsw = tx & 7;

    float4 acc[2][2];
#pragma unroll
    for (int ii = 0; ii < 2; ++ii)
#pragma unroll
        for (int jj = 0; jj < 2; ++jj)
            acc[ii][jj] = make_float4(0.f, 0.f, 0.f, 0.f);

    for (int hc = 0; hc < 4; ++hc) {
#pragma unroll
        for (int u = 0; u < 2; ++u) {
            int idx = tid + u * 256;
            int row = idx >> 4, q = idx & 15;
            int ph = q ^ ((row >> 1) & 7);
            PQbuf[row * 16 + ph]       = *(const float4*)(P + (iBase + row) * 256 + hc * 64 + q * 4);
            PQbuf[512 + row * 16 + ph] = *(const float4*)(Q + (jBase + row) * 256 + hc * 64 + q * 4);
        }
        __syncthreads();

        // uniform pass: relu(P+Q) @ We2
#pragma unroll 4
        for (int q = 0; q < 16; ++q) {
            float4 w2[4];
#pragma unroll
            for (int k = 0; k < 4; ++k)
                w2[k] = *(const float4*)(We2 + (hc * 64 + q * 4 + k) * 4);
            float4 p[2], qv[2];
#pragma unroll
            for (int r = 0; r < 2; ++r) p[r]  = PQbuf[(ty * 2 + r) * 16 + (q ^ psw)];
#pragma unroll
            for (int r = 0; r < 2; ++r) qv[r] = PQbuf[512 + (tx * 2 + r) * 16 + (q ^ qsw)];
#pragma unroll
            for (int ii = 0; ii < 2; ++ii) {
#pragma unroll
                for (int jj = 0; jj < 2; ++jj) {
                    float v0 = fmaxf(p[ii].x + qv[jj].x, 0.f);
                    float v1 = fmaxf(p[ii].y + qv[jj].y, 0.f);
                    float v2 = fmaxf(p[ii].z + qv[jj].z, 0.f);
                    float v3 = fmaxf(p[ii].w + qv[jj].w, 0.f);
                    acc[ii][jj].x += v0 * w2[0].x + v1 * w2[1].x + v2 * w2[2].x + v3 * w2[3].x;
                    acc[ii][jj].y += v0 * w2[0].y + v1 * w2[1].y + v2 * w2[2].y + v3 * w2[3].y;
                    acc[ii][jj].z += v0 * w2[0].z + v1 * w2[1].z + v2 * w2[2].z + v3 * w2[3].z;
                    acc[ii][jj].w += v0 * w2[0].w + v1 * w2[1].w + v2 * w2[2].w + v3 * w2[3].w;
                }
            }
        }

        // sparse fixup: register-resident corrections
#pragma unroll
        for (int k = 0; k < 4; ++k) {
            if (myp[k] < 0) continue;
            const int li = myp[k] >> 5, lj = myp[k] & 31;
            const int ps2 = (li >> 1) & 7, qs2 = (lj >> 1) & 7;
            const float4 a4 = mya[k];
            float4 cc = mycc[k];
#pragma unroll 4
            for (int q = 0; q < 16; ++q) {
                float4 w1[4], w2[4];
#pragma unroll
                for (int c = 0; c < 4; ++c)
                    w1[c] = *(const float4*)(We1 + c * 256 + hc * 64 + q * 4);
#pragma unroll
                for (int kk = 0; kk < 4; ++kk)
                    w2[kk] = *(const float4*)(We2 + (hc * 64 + q * 4 + kk) * 4);
                float4 pv = PQbuf[li * 16 + (q ^ ps2)];
                float4 qv = PQbuf[512 + lj * 16 + (q ^ qs2)];
                float s0 = a4.x * w1[0].x + a4.y * w1[1].x + a4.z * w1[2].x + a4.w * w1[3].x;
                float s1 = a4.x * w1[0].y + a4.y * w1[1].y + a4.z * w1[2].y + a4.w * w1[3].y;
                float s2 = a4.x * w1[0].z + a4.y * w1[1].z + a4.z * w1[2].z + a4.w * w1[3].z;
                float s3 = a4.x * w1[0].w + a4.y * w1[1].w + a4.z * w1[2].w + a4.w * w1[3].w;
                float b0 = pv.x + qv.x, b1 = pv.y + qv.y, b2_ = pv.z + qv.z, b3 = pv.w + qv.w;
                float d0 = fmaxf(b0 + s0, 0.f) - fmaxf(b0, 0.f);
                float d1 = fmaxf(b1 + s1, 0.f) - fmaxf(b1, 0.f);
                float d2 = fmaxf(b2_ + s2, 0.f) - fmaxf(b2_, 0.f);
                float d3 = fmaxf(b3 + s3, 0.f) - fmaxf(b3, 0.f);
                cc.x += d0 * w2[0].x + d1 * w2[1].x + d2 * w2[2].x + d3 * w2[3].x;
                cc.y += d0 * w2[0].y + d1 * w2[1].y + d2 * w2[2].y + d3 * w2[3].y;
                cc.z += d0 * w2[0].z + d1 * w2[1].z + d2 * w2[2].z + d3 * w2[3].z;
                cc.w += d0 * w2[0].w + d1 * w2[1].w + d2 * w2[2].w + d3 * w2[3].w;
            }
            mycc[k] = cc;
        }
        __syncthreads();
    }

    // correction exchange overlaying dead PQbuf
    float4* corr = PQbuf;
#pragma unroll
    for (int u = 0; u < 4; ++u)
        corr[tid + u * 256] = make_float4(0.f, 0.f, 0.f, 0.f);
    __syncthreads();
#pragma unroll
    for (int k = 0; k < 4; ++k)
        if (myp[k] >= 0) corr[myp[k]] = mycc[k];
    __syncthreads();

    const float4 b2 = *(const float4*)be2;
#pragma unroll
    for (int ii = 0; ii < 2; ++ii)
#pragma unroll
        for (int jj = 0; jj < 2; ++jj) {
            int p = (ty * 2 + ii) * 32 + (tx * 2 + jj);
            float4 cr = corr[p];
            float4 o = acc[ii][jj];
            o.x += b2.x + cr.x; o.y += b2.y + cr.y;
            o.z += b2.z + cr.z; o.w += b2.w + cr.w;
            *(float4*)(out + ((size_t)(iBase + ty * 2 + ii) * NN + (jBase + tx * 2 + jj)) * 4) = o;
        }
}

// ---------------------------------------------------------------------------
extern "C" void kernel_launch(void* const* d_in, const int* in_sizes, int n_in,
                              void* d_out, int out_size, void* d_ws, size_t ws_size,
                              hipStream_t stream)
{
    (void)in_sizes; (void)n_in; (void)out_size; (void)ws_size;
    const float* x   = (const float*)d_in[0];
    const int*   ei  = (const int*)d_in[1];
    const float* ew  = (const float*)d_in[2];
    const float* Wn1 = (const float*)d_in[3];
    const float* bn1 = (const float*)d_in[4];
    const float* Wn2 = (const float*)d_in[5];
    const float* bn2 = (const float*)d_in[6];
    const float* We1 = (const float*)d_in[7];
    const float* be1 = (const float*)d_in[8];
    const float* We2 = (const float*)d_in[9];
    const float* be2 = (const float*)d_in[10];
    const float* eps = (const float*)d_in[11];
    float* out = (float*)d_out;

    float* ws = (float*)d_ws;
    int*  partial = (int*)(ws + OFF_PART);
    int*  offs    = (int*)(ws + OFF_OFFS);
    int2* srt     = (int2*)(ws + OFF_SRT);
    float* Pb     = ws + OFF_P;
    float* Qb     = ws + OFF_Q;

    // no memsets needed: every workspace word is fully written before read
    k_hist   <<<64, 1024, 0, stream>>>(ei, partial);
    k_offsets<<<1, 1024, 0, stream>>>(partial, offs);
    k_scatter<<<64, 1024, 0, stream>>>(ei, ew, partial, srt);
    k_node   <<<NN / 4, 1024, 0, stream>>>(x, ei, ew, Wn1, bn1, Wn2, bn2,
                                           We1, be1, eps, Pb, Qb);

    dim3 g(NN / 32, NN / 32);
    k_edge_mlp<<<g, 256, 0, stream>>>(Pb, Qb, offs, srt, We1, We2, be2, out);
}